// Round 4
// baseline (350.904 us; speedup 1.0000x reference)
//
#include <hip/hip_runtime.h>
#include <math.h>

#define NVARS 512
#define HID   16
#define TOPK  8
#define MAGIC0 0x5eedf00du
#define MAGIC1 0xa11ca11eu

// ---------------- Fused kernel: routing (blocks 0..63) + gather-apply --------
// R8. Post-mortem R7: fused_kernel 240us, VALUBusy 2.8% -- the flag spin used
// atomicAdd(p,0) = device-scope RMW from 65536 threads; exit burst alone is
// ~131K serialized RMWs at the coherence point (~hundreds of us). The fusion
// structure itself is sound (all 1024 blocks co-resident: 512thr, VGPR<=64,
// LDS 34KB -> 4 blocks/CU x 256 CU). Fix: poll with RELAXED AGENT-SCOPE
// LOADS (no RMW, broadcast-friendly) + s_sleep backoff; publish unchanged
// (table stores -> __threadfence release -> atomicExch dual magic; 128 RMWs
// total). Consumers stage group-0 into LDS and issue group-1 prefetch BEFORE
// spinning, so the spin overlaps HBM streaming. Producers (blocks 0..63) run
// routing first (smem union with apply tile), then join the same path.
// R7 counters also showed FETCH=37MB << 64MiB x: L3 serves most x re-reads.
// Apply body/barrier proof = R5 (known good): gathers(g) and writes(g+2) to
// the same buffer are separated by the end-of-iteration lgkm barrier.
__global__ __launch_bounds__(512, 8) void fused_kernel(
    const float* __restrict__ x,     // (32768, 512)
    const float* __restrict__ ve,    // (512,16)
    const float* __restrict__ Wq,    // (16,16)
    const float* __restrict__ bq,    // (16,)
    const float* __restrict__ Wk,    // (16,16)
    const float* __restrict__ bk,    // (16,)
    int*   __restrict__ g_idx,       // ws: (512,8)
    float* __restrict__ g_w,         // ws: (512,8)
    unsigned* __restrict__ flags,    // ws: (128,)
    float* __restrict__ out)         // (32768, 512)
{
    // union: routing Ks[512][17] (34816 B)  /  apply xs[2][1024] float4 (32768 B)
    __shared__ __align__(16) unsigned char smem[NVARS * (HID + 1) * 4];

    const int t = threadIdx.x;       // 0..511
    const long base = (long)blockIdx.x * 32;

    // ---- issue group-0 x loads FIRST (independent of everything) ----
    const float* xp = x + base * NVARS + t;
    float v0 = xp[0 * NVARS];
    float v1 = xp[1 * NVARS];
    float v2 = xp[2 * NVARS];
    float v3 = xp[3 * NVARS];
    float v4 = xp[4 * NVARS];
    float v5 = xp[5 * NVARS];
    float v6 = xp[6 * NVARS];
    float v7 = xp[7 * NVARS];

    // ---- producer blocks: routing for rows blockIdx.x*8 .. +7 (uses smem) ----
    if (blockIdx.x < 64) {
        float (*Ks)[HID + 1] = reinterpret_cast<float (*)[HID + 1]>(smem);
        const int wave = t >> 6;
        const int lane = t & 63;
        const int n    = blockIdx.x * 8 + wave;

        float vrow[HID];
        #pragma unroll
        for (int j = 0; j < HID; ++j) vrow[j] = ve[t * HID + j];
        #pragma unroll
        for (int h = 0; h < HID; ++h) {
            float s = bk[h];
            #pragma unroll
            for (int j = 0; j < HID; ++j) s += vrow[j] * Wk[h * HID + j];
            Ks[t][h] = s;
        }

        float q[HID];
        #pragma unroll
        for (int j = 0; j < HID; ++j) vrow[j] = ve[n * HID + j];
        #pragma unroll
        for (int h = 0; h < HID; ++h) {
            float s = bq[h];
            #pragma unroll
            for (int j = 0; j < HID; ++j) s += vrow[j] * Wq[h * HID + j];
            q[h] = s;
        }

        __syncthreads();

        float vals[8];
        #pragma unroll
        for (int i = 0; i < 8; ++i) {
            const int m = i * 64 + lane;
            float s = 0.f;
            #pragma unroll
            for (int h = 0; h < HID; ++h) s += q[h] * Ks[m][h];
            vals[i] = (m == n) ? -1.0e9f : s;
        }

        float mx = 0.f, my_val = 0.f, sum_exp = 0.f;
        int my_idx = 0;
        #pragma unroll
        for (int r = 0; r < TOPK; ++r) {
            float bv = vals[0];
            int   bi = lane;
            #pragma unroll
            for (int i = 1; i < 8; ++i) {
                const int m = i * 64 + lane;
                if (vals[i] > bv) { bv = vals[i]; bi = m; }
            }
            #pragma unroll
            for (int off = 32; off >= 1; off >>= 1) {
                const float ov = __shfl_xor(bv, off);
                const int   oi = __shfl_xor(bi, off);
                if (ov > bv || (ov == bv && oi < bi)) { bv = ov; bi = oi; }
            }
            if (r == 0) mx = bv;
            sum_exp += __expf(bv - mx);
            if (lane == r) { my_val = bv; my_idx = bi; }
            if ((bi & 63) == lane) {
                const int slot = bi >> 6;
                #pragma unroll
                for (int i = 0; i < 8; ++i)
                    if (slot == i) vals[i] = -3.4e38f;
            }
        }

        if (lane < TOPK) {
            g_idx[n * TOPK + lane] = my_idx;
            g_w[n * TOPK + lane]   = __expf(my_val - mx) / sum_exp;
        }

        __syncthreads();                 // Ks reads done; smem free for apply tile
        if (t == 0) {
            __threadfence();             // release: table visible device-wide
            atomicExch(&flags[2 * blockIdx.x + 0], MAGIC0);
            atomicExch(&flags[2 * blockIdx.x + 1], MAGIC1);
        }
    }

    float4* xs = reinterpret_cast<float4*>(smem);   // [buf*1024 + half*512 + col]

    // ---- stage group 0 into buf0 + issue group-1 prefetch, THEN spin ----
    xs[t]       = make_float4(v0, v1, v2, v3);
    xs[512 + t] = make_float4(v4, v5, v6, v7);
    {
        const float* xn = x + (base + 8) * NVARS + t;
        v0 = xn[0 * NVARS];
        v1 = xn[1 * NVARS];
        v2 = xn[2 * NVARS];
        v3 = xn[3 * NVARS];
        v4 = xn[4 * NVARS];
        v5 = xn[5 * NVARS];
        v6 = xn[6 * NVARS];
        v7 = xn[7 * NVARS];
    }

    // ---- wait for all routing chunks: RELAXED AGENT LOADS, no RMW ----
    if (t < 64) {
        long guard = 0;
        for (;;) {
            const unsigned f0 = __hip_atomic_load(&flags[2 * t + 0],
                                  __ATOMIC_RELAXED, __HIP_MEMORY_SCOPE_AGENT);
            const unsigned f1 = __hip_atomic_load(&flags[2 * t + 1],
                                  __ATOMIC_RELAXED, __HIP_MEMORY_SCOPE_AGENT);
            if (f0 == MAGIC0 && f1 == MAGIC1) break;
            __builtin_amdgcn_s_sleep(2);
            if (++guard > (1L << 27)) break;   // never expected; avoids hang
        }
    }
    __syncthreads();                 // group-0 ds_writes done + flags seen
    __threadfence();                 // acquire: invalidate stale cached table

    const int4   i0 = ((const int4*)g_idx)[2 * t + 0];
    const int4   i1 = ((const int4*)g_idx)[2 * t + 1];
    const float4 w0 = ((const float4*)g_w)[2 * t + 0];
    const float4 w1 = ((const float4*)g_w)[2 * t + 1];

    // ---- apply: gather(g) -> write(g+1)/prefetch(g+2) -> store(g) -> barrier ----
    #pragma unroll 1
    for (int g = 0; g < 4; ++g) {
        const float4* buf = xs + (g & 1) * 1024;

        float a0 = 0.f, a1 = 0.f, a2 = 0.f, a3 = 0.f;
        float a4 = 0.f, a5 = 0.f, a6 = 0.f, a7 = 0.f;
        float4 c0, c1;
#define GATH(II, WW)                                                        \
        c0 = buf[II]; c1 = buf[512 + (II)];                                 \
        a0 += c0.x * WW; a1 += c0.y * WW; a2 += c0.z * WW; a3 += c0.w * WW; \
        a4 += c1.x * WW; a5 += c1.y * WW; a6 += c1.z * WW; a7 += c1.w * WW;
        GATH(i0.x, w0.x)
        GATH(i0.y, w0.y)
        GATH(i0.z, w0.z)
        GATH(i0.w, w0.w)
        GATH(i1.x, w1.x)
        GATH(i1.y, w1.y)
        GATH(i1.z, w1.z)
        GATH(i1.w, w1.w)
#undef GATH

        if (g < 3) {
            // stage group g+1 into the other buffer (regs already loaded)
            float4* bn = xs + ((g + 1) & 1) * 1024;
            bn[t]       = make_float4(v0, v1, v2, v3);
            bn[512 + t] = make_float4(v4, v5, v6, v7);
            if (g < 2) {
                const float* xn = x + (base + 8 * (g + 2)) * NVARS + t;
                v0 = xn[0 * NVARS];
                v1 = xn[1 * NVARS];
                v2 = xn[2 * NVARS];
                v3 = xn[3 * NVARS];
                v4 = xn[4 * NVARS];
                v5 = xn[5 * NVARS];
                v6 = xn[6 * NVARS];
                v7 = xn[7 * NVARS];
            }
        }

        float* o = out + (base + 8 * g) * NVARS + t;
        o[0 * NVARS] = a0;
        o[1 * NVARS] = a1;
        o[2 * NVARS] = a2;
        o[3 * NVARS] = a3;
        o[4 * NVARS] = a4;
        o[5 * NVARS] = a5;
        o[6 * NVARS] = a6;
        o[7 * NVARS] = a7;

        // lgkm-only barrier: my gathers(g) + my writes(g+1) retired; after
        // the barrier everyone may gather(g+1); writes(g+2) happen after the
        // NEXT barrier, so gather(g) vs write(g+2) WAR is two barriers apart.
        asm volatile("s_waitcnt lgkmcnt(0)" ::: "memory");
        __builtin_amdgcn_s_barrier();
        asm volatile("" ::: "memory");
    }
}

extern "C" void kernel_launch(void* const* d_in, const int* in_sizes, int n_in,
                              void* d_out, int out_size, void* d_ws, size_t ws_size,
                              hipStream_t stream) {
    const float* x  = (const float*)d_in[0];   // (8,4096,512)
    const float* ve = (const float*)d_in[1];   // (512,16)
    const float* Wq = (const float*)d_in[2];   // (16,16)
    const float* bq = (const float*)d_in[3];   // (16,)
    const float* Wk = (const float*)d_in[4];   // (16,16)
    const float* bk = (const float*)d_in[5];   // (16,)
    float* out = (float*)d_out;

    int*      idx_ws  = (int*)d_ws;
    float*    w_ws    = (float*)((char*)d_ws + NVARS * TOPK * sizeof(int));
    unsigned* flag_ws = (unsigned*)((char*)d_ws + 2 * NVARS * TOPK * sizeof(int));

    fused_kernel<<<1024, 512, 0, stream>>>(x, ve, Wq, bq, Wk, bk,
                                           idx_ws, w_ws, flag_ws, out);
}

// Round 5
// 309.602 us; speedup vs baseline: 1.1334x; 1.1334x over previous
//
#include <hip/hip_runtime.h>
#include <math.h>

#define NVARS 512
#define HID   16
#define TOPK  8
#define MAGIC0 0x5eedf00du

// ---------------- Fused kernel: routing (blocks 0..63) + gather-apply --------
// R9. Sync post-mortems:
//  R7: atomicAdd(p,0) polling = 65K device-scope RMWs -> serialized at the
//      coherence point -> 240us, VALUBusy 2.8%.
//  R8: relaxed agent loads from 64 pollers/block at s_sleep(2) -> ~400
//      coherent loads/cycle at ONE L2 home channel -> FETCH 37->165MB,
//      280us. Mechanism: poller_count x poll_rate must be ~0.
// Fix: ONE poller per block (t==0), ONE aggregate done-word, s_sleep(32)
// backoff -> 0.5 loads/cycle chip-wide (~0.8MB fetch over a 10us spin).
// Producers: table stores -> threadfence (release) -> atomicAdd(count);
// the block seeing old==63 threadfence's and atomicExch's done=MAGIC
// (64 RMWs total). count/done zero-init'd by a 16B hipMemsetAsync (ws is
// poisoned; harness's own reset enqueues memsets, capture-safe).
// Co-residency (validated by R7/R8 passing): 512thr, launch_bounds(512,8)
// => VGPR<=64; LDS 34816B => 4 blocks/CU x 256 CU = 1024 = grid, so all
// blocks resident at t0 and the spin cannot deadlock.
// Apply loop = byte-identical R5 structure (139.19us two-kernel version):
// write(g) -> prefetch(g+1) -> lgkm-only barrier -> gather(g) -> store(g).
__global__ __launch_bounds__(512, 8) void fused_kernel(
    const float* __restrict__ x,     // (32768, 512)
    const float* __restrict__ ve,    // (512,16)
    const float* __restrict__ Wq,    // (16,16)
    const float* __restrict__ bq,    // (16,)
    const float* __restrict__ Wk,    // (16,16)
    const float* __restrict__ bk,    // (16,)
    int*   __restrict__ g_idx,       // ws: (512,8)
    float* __restrict__ g_w,         // ws: (512,8)
    unsigned* __restrict__ flags,    // ws: [0]=done [1]=count (memset to 0)
    float* __restrict__ out)         // (32768, 512)
{
    // union: routing Ks[512][17] (34816 B) / apply xs[2][1024] float4 (32768 B)
    __shared__ __align__(16) unsigned char smem[NVARS * (HID + 1) * 4];

    const int t = threadIdx.x;       // 0..511
    const long base = (long)blockIdx.x * 32;

    // ---- issue group-0 x loads FIRST (independent of routing/spin) ----
    const float* xp = x + base * NVARS + t;
    float v0 = xp[0 * NVARS];
    float v1 = xp[1 * NVARS];
    float v2 = xp[2 * NVARS];
    float v3 = xp[3 * NVARS];
    float v4 = xp[4 * NVARS];
    float v5 = xp[5 * NVARS];
    float v6 = xp[6 * NVARS];
    float v7 = xp[7 * NVARS];

    // ---- producer blocks: routing for rows blockIdx.x*8 .. +7 ----
    if (blockIdx.x < 64) {
        float (*Ks)[HID + 1] = reinterpret_cast<float (*)[HID + 1]>(smem);
        const int wave = t >> 6;
        const int lane = t & 63;
        const int n    = blockIdx.x * 8 + wave;

        float vrow[HID];
        #pragma unroll
        for (int j = 0; j < HID; ++j) vrow[j] = ve[t * HID + j];
        #pragma unroll
        for (int h = 0; h < HID; ++h) {
            float s = bk[h];
            #pragma unroll
            for (int j = 0; j < HID; ++j) s += vrow[j] * Wk[h * HID + j];
            Ks[t][h] = s;
        }

        float q[HID];
        #pragma unroll
        for (int j = 0; j < HID; ++j) vrow[j] = ve[n * HID + j];
        #pragma unroll
        for (int h = 0; h < HID; ++h) {
            float s = bq[h];
            #pragma unroll
            for (int j = 0; j < HID; ++j) s += vrow[j] * Wq[h * HID + j];
            q[h] = s;
        }

        __syncthreads();

        float vals[8];
        #pragma unroll
        for (int i = 0; i < 8; ++i) {
            const int m = i * 64 + lane;
            float s = 0.f;
            #pragma unroll
            for (int h = 0; h < HID; ++h) s += q[h] * Ks[m][h];
            vals[i] = (m == n) ? -1.0e9f : s;
        }

        float mx = 0.f, my_val = 0.f, sum_exp = 0.f;
        int my_idx = 0;
        #pragma unroll
        for (int r = 0; r < TOPK; ++r) {
            float bv = vals[0];
            int   bi = lane;
            #pragma unroll
            for (int i = 1; i < 8; ++i) {
                const int m = i * 64 + lane;
                if (vals[i] > bv) { bv = vals[i]; bi = m; }
            }
            #pragma unroll
            for (int off = 32; off >= 1; off >>= 1) {
                const float ov = __shfl_xor(bv, off);
                const int   oi = __shfl_xor(bi, off);
                if (ov > bv || (ov == bv && oi < bi)) { bv = ov; bi = oi; }
            }
            if (r == 0) mx = bv;
            sum_exp += __expf(bv - mx);
            if (lane == r) { my_val = bv; my_idx = bi; }
            if ((bi & 63) == lane) {
                const int slot = bi >> 6;
                #pragma unroll
                for (int i = 0; i < 8; ++i)
                    if (slot == i) vals[i] = -3.4e38f;
            }
        }

        if (lane < TOPK) {
            g_idx[n * TOPK + lane] = my_idx;
            g_w[n * TOPK + lane]   = __expf(my_val - mx) / sum_exp;
        }

        __syncthreads();                 // Ks reads done; smem free for apply
        if (t == 0) {
            __threadfence();             // release my table rows
            const unsigned old = atomicAdd(&flags[1], 1u);
            if (old == 63u) {            // I observed all 64 publishes
                __threadfence();
                atomicExch(&flags[0], MAGIC0);
            }
        }
    }

    // ---- wait: ONE poller per block, low-rate relaxed agent loads ----
    if (t == 0) {
        long guard = 0;
        while (__hip_atomic_load(&flags[0], __ATOMIC_RELAXED,
                                 __HIP_MEMORY_SCOPE_AGENT) != MAGIC0) {
            __builtin_amdgcn_s_sleep(32);        // ~2048 clk between polls
            if (++guard > (1L << 21)) break;     // never expected; avoids hang
        }
    }
    __syncthreads();
    __threadfence();                     // acquire: discard stale cached table

    const int4   i0 = ((const int4*)g_idx)[2 * t + 0];
    const int4   i1 = ((const int4*)g_idx)[2 * t + 1];
    const float4 w0 = ((const float4*)g_w)[2 * t + 0];
    const float4 w1 = ((const float4*)g_w)[2 * t + 1];

    // ---- apply: EXACT R5 loop (known-good at 139.19us in two-kernel form) ----
    float4* xs = reinterpret_cast<float4*>(smem);   // [buf*1024 + half*512 + col]

    #pragma unroll 1
    for (int g = 0; g < 4; ++g) {
        float4* buf = xs + (g & 1) * 1024;
        buf[t]       = make_float4(v0, v1, v2, v3);
        buf[512 + t] = make_float4(v4, v5, v6, v7);

        if (g < 3) {
            const float* xn = x + (base + 8 * (g + 1)) * NVARS + t;
            v0 = xn[0 * NVARS];
            v1 = xn[1 * NVARS];
            v2 = xn[2 * NVARS];
            v3 = xn[3 * NVARS];
            v4 = xn[4 * NVARS];
            v5 = xn[5 * NVARS];
            v6 = xn[6 * NVARS];
            v7 = xn[7 * NVARS];
        }

        asm volatile("s_waitcnt lgkmcnt(0)" ::: "memory");
        __builtin_amdgcn_s_barrier();
        asm volatile("" ::: "memory");

        float a0 = 0.f, a1 = 0.f, a2 = 0.f, a3 = 0.f;
        float a4 = 0.f, a5 = 0.f, a6 = 0.f, a7 = 0.f;
        float4 c0, c1;
#define GATH(II, WW)                                                        \
        c0 = buf[II]; c1 = buf[512 + (II)];                                 \
        a0 += c0.x * WW; a1 += c0.y * WW; a2 += c0.z * WW; a3 += c0.w * WW; \
        a4 += c1.x * WW; a5 += c1.y * WW; a6 += c1.z * WW; a7 += c1.w * WW;
        GATH(i0.x, w0.x)
        GATH(i0.y, w0.y)
        GATH(i0.z, w0.z)
        GATH(i0.w, w0.w)
        GATH(i1.x, w1.x)
        GATH(i1.y, w1.y)
        GATH(i1.z, w1.z)
        GATH(i1.w, w1.w)
#undef GATH

        float* o = out + (base + 8 * g) * NVARS + t;
        o[0 * NVARS] = a0;
        o[1 * NVARS] = a1;
        o[2 * NVARS] = a2;
        o[3 * NVARS] = a3;
        o[4 * NVARS] = a4;
        o[5 * NVARS] = a5;
        o[6 * NVARS] = a6;
        o[7 * NVARS] = a7;
        // no trailing barrier: next ds_writes hit the other buffer; same-
        // buffer WAR is separated by the next lgkm barrier.
    }
}

extern "C" void kernel_launch(void* const* d_in, const int* in_sizes, int n_in,
                              void* d_out, int out_size, void* d_ws, size_t ws_size,
                              hipStream_t stream) {
    const float* x  = (const float*)d_in[0];   // (8,4096,512)
    const float* ve = (const float*)d_in[1];   // (512,16)
    const float* Wq = (const float*)d_in[2];   // (16,16)
    const float* bq = (const float*)d_in[3];   // (16,)
    const float* Wk = (const float*)d_in[4];   // (16,16)
    const float* bk = (const float*)d_in[5];   // (16,)
    float* out = (float*)d_out;

    int*      idx_ws  = (int*)d_ws;                               // 16 KB
    float*    w_ws    = (float*)((char*)d_ws + 16384);            // 16 KB
    unsigned* flag_ws = (unsigned*)((char*)d_ws + 32768);         // 16 B

    hipMemsetAsync(flag_ws, 0, 16, stream);   // zero done+count (ws is poisoned)
    fused_kernel<<<1024, 512, 0, stream>>>(x, ve, Wq, bq, Wk, bk,
                                           idx_ws, w_ws, flag_ws, out);
}

// Round 6
// 141.391 us; speedup vs baseline: 2.4818x; 2.1897x over previous
//
#include <hip/hip_runtime.h>
#include <hip/hip_bf16.h>
#include <math.h>

#define NVARS 512
#define HID   16
#define TOPK  8

// ---------------- Kernel 1: routing (Q/K proj, sim, top-8, softmax) ----------
// Grid: 64 blocks x 512 threads. Wave w of block b handles row n = b*8 + w.
__global__ __launch_bounds__(512) void routing_kernel(
    const float* __restrict__ ve,   // (512,16)
    const float* __restrict__ Wq,   // (16,16)
    const float* __restrict__ bq,   // (16,)
    const float* __restrict__ Wk,   // (16,16)
    const float* __restrict__ bk,   // (16,)
    int*   __restrict__ out_idx,    // (512,8)
    float* __restrict__ out_w)      // (512,8)
{
    __shared__ float Ks[NVARS][HID + 1];   // stride 17 -> conflict-free

    const int t    = threadIdx.x;          // 0..511
    const int wave = t >> 6;               // 0..7
    const int lane = t & 63;
    const int n    = blockIdx.x * 8 + wave;  // row this wave owns

    // --- K[t][:] into LDS (each thread computes one K row) ---
    float vrow[HID];
    #pragma unroll
    for (int j = 0; j < HID; ++j) vrow[j] = ve[t * HID + j];
    #pragma unroll
    for (int h = 0; h < HID; ++h) {
        float s = bk[h];
        #pragma unroll
        for (int j = 0; j < HID; ++j) s += vrow[j] * Wk[h * HID + j];
        Ks[t][h] = s;
    }

    // --- Q[n][:] redundantly per lane (uniform loads, broadcast) ---
    float q[HID];
    #pragma unroll
    for (int j = 0; j < HID; ++j) vrow[j] = ve[n * HID + j];
    #pragma unroll
    for (int h = 0; h < HID; ++h) {
        float s = bq[h];
        #pragma unroll
        for (int j = 0; j < HID; ++j) s += vrow[j] * Wq[h * HID + j];
        q[h] = s;
    }

    __syncthreads();

    // --- sims for m = i*64 + lane (8 per lane = full 512 per wave) ---
    float vals[8];
    #pragma unroll
    for (int i = 0; i < 8; ++i) {
        const int m = i * 64 + lane;
        float s = 0.f;
        #pragma unroll
        for (int h = 0; h < HID; ++h) s += q[h] * Ks[m][h];
        vals[i] = (m == n) ? -1.0e9f : s;
    }

    // --- 8 rounds of wave-wide argmax (top-8) ---
    float mx = 0.f, my_val = 0.f, sum_exp = 0.f;
    int my_idx = 0;
    #pragma unroll
    for (int r = 0; r < TOPK; ++r) {
        float bv = vals[0];
        int   bi = lane;                    // m = 0*64 + lane
        #pragma unroll
        for (int i = 1; i < 8; ++i) {
            const int m = i * 64 + lane;
            if (vals[i] > bv) { bv = vals[i]; bi = m; }   // strict > keeps lowest m on tie
        }
        #pragma unroll
        for (int off = 32; off >= 1; off >>= 1) {
            const float ov = __shfl_xor(bv, off);
            const int   oi = __shfl_xor(bi, off);
            if (ov > bv || (ov == bv && oi < bi)) { bv = ov; bi = oi; }
        }
        // all lanes now hold round-r winner (bv, bi)
        if (r == 0) mx = bv;
        sum_exp += __expf(bv - mx);
        if (lane == r) { my_val = bv; my_idx = bi; }
        // owner lane retires the winner
        if ((bi & 63) == lane) {
            const int slot = bi >> 6;
            #pragma unroll
            for (int i = 0; i < 8; ++i)
                if (slot == i) vals[i] = -3.4e38f;
        }
    }

    if (lane < TOPK) {
        out_idx[n * TOPK + lane] = my_idx;
        out_w[n * TOPK + lane]   = __expf(my_val - mx) / sum_exp;
    }
}

// ---------------- Kernel 2: gather-weighted sum over rows --------------------
// EXACT R5 structure -- best measured artifact (139.19 us total, passed).
// 1024 blocks x 512 threads; 32 rows/block in 8-row groups; LDS transposed
// (xs[buf][half][col] = float4 of 4 rows at column col) so one random-column
// gather is a single ds_read_b128 serving 4 rows; double-buffered; ONE
// lgkm-only barrier per group (vmcnt never drained at the barrier).
// Measured dead ends -- do not retry without new counter evidence:
//  - 16x full-drain __syncthreads (R2 base): equal (139.25). Barrier cost is
//    hidden by 32 waves/CU TLP.
//  - b64 gather with 40B stride / 16 bank classes (R6): +5.5us. LDS cost =
//    issue count x per-instr cycles; b128's random-gather conflicts are ~free
//    vs its bytes floor, and 64 b128 reads/thread-tile is the floor.
//  - Fused single-launch producer/consumer (R7/R8/R9): 233-280us. Three sync
//    variants, three counter-diagnosed mechanisms (RMW serialization; poll
//    load-storm at one L2 home channel; stale per-XCD L2 line never
//    invalidated by device-scope atomicExch -> ~200us eviction-bound spin).
//    Cross-block flag sync >= 100us at this grid scale vs ~8-10us available.
__global__ __launch_bounds__(512) void apply_kernel(
    const float* __restrict__ x,     // (32768, 512)
    const int*   __restrict__ gidx,  // (512, 8)
    const float* __restrict__ gw,    // (512, 8)
    float*       __restrict__ out)   // (32768, 512)
{
    __shared__ float4 xs[2][2][NVARS];  // [buf][rowhalf][col] : 32 KB

    const int t = threadIdx.x;       // thread t owns column t (all rows)
    const int4   i0 = ((const int4*)gidx)[2 * t + 0];
    const int4   i1 = ((const int4*)gidx)[2 * t + 1];
    const float4 w0 = ((const float4*)gw)[2 * t + 0];
    const float4 w1 = ((const float4*)gw)[2 * t + 1];

    const long base = (long)blockIdx.x * 32;

    // preload group 0: column t of rows base..base+7 (coalesced dword loads)
    const float* xp = x + base * NVARS + t;
    float v0 = xp[0 * NVARS];
    float v1 = xp[1 * NVARS];
    float v2 = xp[2 * NVARS];
    float v3 = xp[3 * NVARS];
    float v4 = xp[4 * NVARS];
    float v5 = xp[5 * NVARS];
    float v6 = xp[6 * NVARS];
    float v7 = xp[7 * NVARS];

    #pragma unroll 1
    for (int g = 0; g < 4; ++g) {
        float4 (*buf)[NVARS] = xs[g & 1];
        buf[0][t] = make_float4(v0, v1, v2, v3);   // conflict-free b128 writes
        buf[1][t] = make_float4(v4, v5, v6, v7);

        // issue next group's prefetch BEFORE the barrier -- nothing drains
        // vmcnt at the barrier, so these flow across it.
        if (g < 3) {
            const float* xn = x + (base + 8 * (g + 1)) * NVARS + t;
            v0 = xn[0 * NVARS];
            v1 = xn[1 * NVARS];
            v2 = xn[2 * NVARS];
            v3 = xn[3 * NVARS];
            v4 = xn[4 * NVARS];
            v5 = xn[5 * NVARS];
            v6 = xn[6 * NVARS];
            v7 = xn[7 * NVARS];
        }

        // lgkm-only barrier: ds_writes of this group done + this wave's
        // gathers of group g-1 retired; do NOT drain vmcnt.
        asm volatile("s_waitcnt lgkmcnt(0)" ::: "memory");
        __builtin_amdgcn_s_barrier();
        asm volatile("" ::: "memory");   // no LDS op may hoist above barrier

        float a0 = 0.f, a1 = 0.f, a2 = 0.f, a3 = 0.f;
        float a4 = 0.f, a5 = 0.f, a6 = 0.f, a7 = 0.f;
        float4 c0, c1;
#define GATH(II, WW)                                                     \
        c0 = buf[0][II]; c1 = buf[1][II];                                \
        a0 += c0.x * WW; a1 += c0.y * WW; a2 += c0.z * WW; a3 += c0.w * WW; \
        a4 += c1.x * WW; a5 += c1.y * WW; a6 += c1.z * WW; a7 += c1.w * WW;
        GATH(i0.x, w0.x)
        GATH(i0.y, w0.y)
        GATH(i0.z, w0.z)
        GATH(i0.w, w0.w)
        GATH(i1.x, w1.x)
        GATH(i1.y, w1.y)
        GATH(i1.z, w1.z)
        GATH(i1.w, w1.w)
#undef GATH

        float* o = out + (base + 8 * g) * NVARS + t;
        o[0 * NVARS] = a0;
        o[1 * NVARS] = a1;
        o[2 * NVARS] = a2;
        o[3 * NVARS] = a3;
        o[4 * NVARS] = a4;
        o[5 * NVARS] = a5;
        o[6 * NVARS] = a6;
        o[7 * NVARS] = a7;
        // no trailing barrier: next iteration's ds_writes target the other
        // buffer; same-buffer WAR is separated by the next barrier.
    }
}

extern "C" void kernel_launch(void* const* d_in, const int* in_sizes, int n_in,
                              void* d_out, int out_size, void* d_ws, size_t ws_size,
                              hipStream_t stream) {
    const float* x  = (const float*)d_in[0];   // (8,4096,512)
    const float* ve = (const float*)d_in[1];   // (512,16)
    const float* Wq = (const float*)d_in[2];   // (16,16)
    const float* bq = (const float*)d_in[3];   // (16,)
    const float* Wk = (const float*)d_in[4];   // (16,16)
    const float* bk = (const float*)d_in[5];   // (16,)
    float* out = (float*)d_out;

    int*   idx_ws = (int*)d_ws;
    float* w_ws   = (float*)((char*)d_ws + NVARS * TOPK * sizeof(int));

    routing_kernel<<<64, 512, 0, stream>>>(ve, Wq, bq, Wk, bk, idx_ws, w_ws);
    apply_kernel<<<1024, 512, 0, stream>>>(x, idx_ws, w_ws, out);
}